// Round 4
// baseline (1877.941 us; speedup 1.0000x reference)
//
#include <hip/hip_runtime.h>

// B=2, T=2048, E=1024, H=8, D=512, HD=4096. bf16 MFMA internally.

#define DEV __device__ __forceinline__

using bf16x8  = __attribute__((ext_vector_type(8))) short;
using floatx4 = __attribute__((ext_vector_type(4))) float;

#define MFMA16(a, b, c) __builtin_amdgcn_mfma_f32_16x16x32_bf16((a), (b), (c), 0, 0, 0)

DEV unsigned short f2bf(float f) {
  union { float f; unsigned int u; } c; c.f = f;
  unsigned int u = c.u + 0x7FFFu + ((c.u >> 16) & 1u);
  return (unsigned short)(u >> 16);
}
DEV float bf2f(unsigned short h) {
  union { unsigned int u; float f; } c; c.u = ((unsigned int)h) << 16;
  return c.f;
}

// async global->LDS, 16B per lane. LDS dest = wave-uniform base + lane*16.
DEV void ldsld16(const unsigned short* g, unsigned short* l) {
  __builtin_amdgcn_global_load_lds(
      (__attribute__((address_space(1))) void*)(g),
      (__attribute__((address_space(3))) void*)(l), 16, 0, 0);
}

// ---------------- fused cast fp32 -> bf16 for all 5 tensors ----------------
__global__ void cast5_k(const float* __restrict__ x,  const float* __restrict__ wq,
                        const float* __restrict__ wk, const float* __restrict__ wv,
                        const float* __restrict__ wo,
                        unsigned short* __restrict__ xb,  unsigned short* __restrict__ wqb,
                        unsigned short* __restrict__ wkb, unsigned short* __restrict__ wvb,
                        unsigned short* __restrict__ wob) {
  const float* s; unsigned short* d;
  switch (blockIdx.y) {
    case 0: s = x;  d = xb;  break;
    case 1: s = wq; d = wqb; break;
    case 2: s = wk; d = wkb; break;
    case 3: s = wv; d = wvb; break;
    default: s = wo; d = wob; break;
  }
  int i = blockIdx.x * 256 + threadIdx.x;
  float4 v = ((const float4*)s)[i];
  uint2 o;
  o.x = (unsigned int)f2bf(v.x) | ((unsigned int)f2bf(v.y) << 16);
  o.y = (unsigned int)f2bf(v.z) | ((unsigned int)f2bf(v.w) << 16);
  ((uint2*)d)[i] = o;
}

// ---------------- QKV projection GEMM ----------------
// Q,K -> [B,H,T,D]. V -> slab layout [BH][T/32][D][32] (coalesced flash reads).
__global__ __launch_bounds__(256) void qkv_gemm(
    const unsigned short* __restrict__ X,
    const unsigned short* __restrict__ Wq, const unsigned short* __restrict__ Wk,
    const unsigned short* __restrict__ Wv,
    unsigned short* __restrict__ Qo, unsigned short* __restrict__ Ko, unsigned short* __restrict__ Vo) {
  __shared__ __align__(16) unsigned short As[128 * 32];
  __shared__ __align__(16) unsigned short Bs[128 * 32];
  const int tid = threadIdx.x;
  const int wave = tid >> 6, lane = tid & 63, quad = lane >> 4, l16 = lane & 15;
  const int m0 = blockIdx.x * 128, n0 = blockIdx.y * 128;
  const int z = blockIdx.z;
  const unsigned short* W = (z == 0) ? Wq : (z == 1) ? Wk : Wv;
  const int wm = (wave >> 1) * 64, wn = (wave & 1) * 64;
  floatx4 acc[4][4];
#pragma unroll
  for (int i = 0; i < 4; ++i)
#pragma unroll
    for (int j = 0; j < 4; ++j) acc[i][j] = (floatx4){0.f, 0.f, 0.f, 0.f};

  const int r0 = wave * 32;
  const int lrow = lane >> 2, lchunk = (lane & 3) * 8;
  for (int k0 = 0; k0 < 1024; k0 += 32) {
    const unsigned short* ga = X + (size_t)(m0 + r0 + lrow) * 1024 + k0 + lchunk;
    const unsigned short* gb = W + (size_t)(n0 + r0 + lrow) * 1024 + k0 + lchunk;
    ldsld16(ga, As + r0 * 32);
    ldsld16(ga + (size_t)16 * 1024, As + r0 * 32 + 512);
    ldsld16(gb, Bs + r0 * 32);
    ldsld16(gb + (size_t)16 * 1024, Bs + r0 * 32 + 512);
    __syncthreads();
    bf16x8 af[4], bw[4];
#pragma unroll
    for (int i = 0; i < 4; ++i) af[i] = *(const bf16x8*)(As + (wm + i * 16 + l16) * 32 + quad * 8);
#pragma unroll
    for (int j = 0; j < 4; ++j) bw[j] = *(const bf16x8*)(Bs + (wn + j * 16 + l16) * 32 + quad * 8);
#pragma unroll
    for (int i = 0; i < 4; ++i)
#pragma unroll
      for (int j = 0; j < 4; ++j) acc[i][j] = MFMA16(af[i], bw[j], acc[i][j]);
    __syncthreads();
  }
#pragma unroll
  for (int i = 0; i < 4; ++i)
#pragma unroll
    for (int j = 0; j < 4; ++j) {
      int gn = n0 + wn + j * 16 + l16;
      int h = gn >> 9, d = gn & 511;
      int gm0 = m0 + wm + i * 16 + quad * 4;
      int b = gm0 >> 11, t0 = gm0 & 2047;
      if (z == 2) {
        unsigned short pk[4];
#pragma unroll
        for (int r = 0; r < 4; ++r) pk[r] = f2bf(acc[i][j][r]);
        size_t off = ((size_t)((b * 8 + h) * 64 + (t0 >> 5))) * 16384 + (size_t)d * 32 + (t0 & 31);
        *(uint2*)(Vo + off) = *(uint2*)pk;   // packed 8B slab write
      } else {
        unsigned short* P = (z == 0) ? Qo : Ko;
        size_t base = ((size_t)((b * 8 + h) * 2048 + t0)) * 512 + d;
#pragma unroll
        for (int r = 0; r < 4; ++r) P[base + (size_t)r * 512] = f2bf(acc[i][j][r]);
      }
    }
}

// ---------------- RoPE (Q,K only; V slab untouched) ----------------
__global__ void rope_k(unsigned short* __restrict__ Q, unsigned short* __restrict__ K) {
  int idx = blockIdx.x * 256 + threadIdx.x;
  unsigned short* P = (idx & 8388608) ? K : Q;
  int r = idx & 8388607;
  int row = r >> 8;
  int i = r & 255;
  int t = row & 2047;
  size_t base = (size_t)row * 512;
  float x1 = bf2f(P[base + i]);
  float x2 = bf2f(P[base + i + 256]);
  float freq = expf(-(float)i * 0.03597789207803197f);
  float ang = (float)t * freq;
  float sv, cv;
  sincosf(ang, &sv, &cv);
  P[base + i]       = f2bf(x1 * cv - x2 * sv);
  P[base + i + 256] = f2bf(x1 * sv + x2 * cv);
}

// ---------------- flash attention v4: barrier-free ----------------
// WG = 128 threads = 2 independent waves. Wave owns 16 q-rows x full 512 d.
// K,V fragments read directly from global (L2/L3); only LDS is a per-wave
// private P tile (stride-72 padding). NO __syncthreads anywhere.
// grid (16 bh, jobs). q-tile 32 rows; s-tile 64; qi>=32 split into 2 s-chunks.
__global__ __launch_bounds__(128, 2) void flash_attn(
    const unsigned short* __restrict__ Q, const unsigned short* __restrict__ K,
    const unsigned short* __restrict__ Vslab, unsigned short* __restrict__ attn,
    unsigned short* __restrict__ P1, float* __restrict__ ml1, float* __restrict__ ml2,
    int split) {
  __shared__ __align__(16) unsigned short Ps[2 * 16 * 72];  // per-wave [16][72-pad]
  const int tid = threadIdx.x;
  const int wave = tid >> 6, lane = tid & 63, quad = lane >> 4, l16 = lane & 15;
  const int bh = blockIdx.x, b = bh >> 3, head = bh & 7;
  const int y = blockIdx.y;
  int qi, st0, stN, om;  // om: 0 direct, 1 chunk0->P1, 2 chunk1->attn unnormalized
  if (split) {
    if (y < 64) {
      qi = 63 - (y >> 1);
      int tot = (qi >> 1) + 1, mid = tot >> 1;
      if ((y & 1) == 0) { st0 = 0;   stN = mid; om = 1; }
      else              { st0 = mid; stN = tot; om = 2; }
    } else { qi = 95 - y; st0 = 0; stN = (qi >> 1) + 1; om = 0; }
  } else { qi = 63 - y; st0 = 0; stN = (qi >> 1) + 1; om = 0; }

  const size_t bhoff = (size_t)bh << 20;
  const unsigned short* Qp = Q + bhoff;
  const unsigned short* Kp = K + bhoff;
  const unsigned short* Vp = Vslab + bhoff;
  const int qb = qi * 32;
  const int qw0 = qb + wave * 16;         // wave's first q-row

  // Q fragments: 16 k-steps (A-frag: m=l16, k=quad*8+j)
  bf16x8 qf[16];
  {
    const unsigned short* qrow = Qp + (size_t)(qw0 + l16) * 512 + quad * 8;
#pragma unroll
    for (int ks = 0; ks < 16; ++ks) qf[ks] = *(const bf16x8*)(qrow + ks * 32);
  }
  floatx4 o[32];
#pragma unroll
  for (int n = 0; n < 32; ++n) o[n] = (floatx4){0.f, 0.f, 0.f, 0.f};
  float m_[4], l_[4];
#pragma unroll
  for (int r = 0; r < 4; ++r) { m_[r] = -3.0e38f; l_[r] = 0.f; }

  unsigned short* psw = Ps + wave * 1152;  // 16 rows x 72

  for (int st = st0; st < stN; ++st) {
    const int s0 = st * 64;
    // ---- QK: S[16q][64s] over full 512 d, K direct from global ----
    floatx4 sc[4];
#pragma unroll
    for (int c = 0; c < 4; ++c) sc[c] = (floatx4){0.f, 0.f, 0.f, 0.f};
    const unsigned short* kr0 = Kp + (size_t)(s0 + l16) * 512 + quad * 8;
#pragma unroll 4
    for (int ks = 0; ks < 16; ++ks) {
      bf16x8 k0 = *(const bf16x8*)(kr0 + ks * 32);
      bf16x8 k1 = *(const bf16x8*)(kr0 + 16 * 512 + ks * 32);
      bf16x8 k2 = *(const bf16x8*)(kr0 + 32 * 512 + ks * 32);
      bf16x8 k3 = *(const bf16x8*)(kr0 + 48 * 512 + ks * 32);
      sc[0] = MFMA16(qf[ks], k0, sc[0]);
      sc[1] = MFMA16(qf[ks], k1, sc[1]);
      sc[2] = MFMA16(qf[ks], k2, sc[2]);
      sc[3] = MFMA16(qf[ks], k3, sc[3]);
    }
    // ---- softmax over 64 cols (rows quad*4+r, col block c at s0+c*16+l16) ----
    const float scale = 0.04419417382415922f;  // 1/sqrt(512)
    const bool need_mask = (s0 + 63 > qw0);    // wave-uniform: only diagonal tile
    float mr[4];
#pragma unroll
    for (int r = 0; r < 4; ++r) mr[r] = -3.0e38f;
#pragma unroll
    for (int c = 0; c < 4; ++c) {
      int scol = s0 + c * 16 + l16;
#pragma unroll
      for (int r = 0; r < 4; ++r) {
        float a = sc[c][r] * scale;
        if (need_mask && scol > qw0 + quad * 4 + r) a = -3.0e38f;
        sc[c][r] = a;
        mr[r] = fmaxf(mr[r], a);
      }
    }
#pragma unroll
    for (int off = 1; off < 16; off <<= 1)
#pragma unroll
      for (int r = 0; r < 4; ++r) mr[r] = fmaxf(mr[r], __shfl_xor(mr[r], off, 64));
    float alpha[4], rs[4];
#pragma unroll
    for (int r = 0; r < 4; ++r) {
      float mn = fmaxf(m_[r], mr[r]);
      alpha[r] = __expf(m_[r] - mn);
      m_[r] = mn;
      rs[r] = 0.f;
    }
#pragma unroll
    for (int c = 0; c < 4; ++c)
#pragma unroll
      for (int r = 0; r < 4; ++r) {
        float p = __expf(sc[c][r] - m_[r]);
        rs[r] += p;
        psw[(quad * 4 + r) * 72 + c * 16 + l16] = f2bf(p);
      }
#pragma unroll
    for (int off = 1; off < 16; off <<= 1)
#pragma unroll
      for (int r = 0; r < 4; ++r) rs[r] += __shfl_xor(rs[r], off, 64);
#pragma unroll
    for (int r = 0; r < 4; ++r) l_[r] = l_[r] * alpha[r] + rs[r];
    // skip O-rescale when no row max moved
    if (__any(alpha[0] + alpha[1] + alpha[2] + alpha[3] < 4.0f)) {
#pragma unroll
      for (int n = 0; n < 32; ++n)
#pragma unroll
        for (int r = 0; r < 4; ++r) o[n][r] *= alpha[r];
    }
    // ---- PV: O[16][512] += P[16][64] * V[64][512], V direct from slab ----
    bf16x8 pf0 = *(const bf16x8*)(psw + l16 * 72 + quad * 8);        // s 0..31
    bf16x8 pf1 = *(const bf16x8*)(psw + l16 * 72 + 32 + quad * 8);   // s 32..63
#pragma unroll
    for (int c2 = 0; c2 < 2; ++c2) {
      bf16x8 pf = c2 ? pf1 : pf0;
      const unsigned short* vb = Vp + (size_t)(2 * st + c2) * 16384 + (size_t)l16 * 32 + quad * 8;
#pragma unroll 8
      for (int nt = 0; nt < 32; ++nt) {
        bf16x8 vf = *(const bf16x8*)(vb + (size_t)nt * 512);
        o[nt] = MFMA16(pf, vf, o[nt]);
      }
    }
  }
  // ---- outputs ----
  const int rbase = wave * 16 + quad * 4;  // row within 32-row q-tile, +r
  const int p1i = bh * 32 + (qi - 32);
  if (om == 1) {
    unsigned short* prow = P1 + ((size_t)p1i * 32 + rbase) * 512 + l16;
#pragma unroll
    for (int nt = 0; nt < 32; ++nt)
#pragma unroll
      for (int r = 0; r < 4; ++r)
        prow[(size_t)r * 512 + nt * 16] = f2bf(o[nt][r]);   // unnormalized
  } else {
    unsigned short* arow =
        attn + ((size_t)(b * 2048 + qb + rbase)) * 4096 + head * 512 + l16;
    if (om == 0) {
      float inv[4];
#pragma unroll
      for (int r = 0; r < 4; ++r) inv[r] = 1.0f / l_[r];
#pragma unroll
      for (int nt = 0; nt < 32; ++nt)
#pragma unroll
        for (int r = 0; r < 4; ++r)
          arow[(size_t)r * 4096 + nt * 16] = f2bf(o[nt][r] * inv[r]);
    } else {
#pragma unroll
      for (int nt = 0; nt < 32; ++nt)
#pragma unroll
        for (int r = 0; r < 4; ++r)
          arow[(size_t)r * 4096 + nt * 16] = f2bf(o[nt][r]);  // unnormalized
    }
  }
  if (om != 0 && l16 == 0) {
    float* ml = (om == 1) ? ml1 : ml2;
#pragma unroll
    for (int r = 0; r < 4; ++r) {
      ml[(size_t)p1i * 64 + (rbase + r) * 2]     = m_[r];
      ml[(size_t)p1i * 64 + (rbase + r) * 2 + 1] = l_[r];
    }
  }
}

// ---------------- combine split partials (qi>=32) ----------------
__global__ void combine_k(const unsigned short* __restrict__ P1,
                          const float* __restrict__ ml1, const float* __restrict__ ml2,
                          unsigned short* __restrict__ attn) {
  const int p = blockIdx.x;  // [0,512)
  const int bh = p >> 5, qi = 32 + (p & 31), b = bh >> 3, head = bh & 7;
  const int tid = threadIdx.x;
#pragma unroll
  for (int it = 0; it < 8; ++it) {
    int idx = it * 256 + tid;        // 32 rows * 64 chunks
    int row = idx >> 6, c8 = (idx & 63) * 8;
    float m1 = ml1[(size_t)p * 64 + row * 2], l1 = ml1[(size_t)p * 64 + row * 2 + 1];
    float m2 = ml2[(size_t)p * 64 + row * 2], l2 = ml2[(size_t)p * 64 + row * 2 + 1];
    float M = fmaxf(m1, m2);
    float w1 = __expf(m1 - M), w2 = __expf(m2 - M);
    float inv = 1.0f / (l1 * w1 + l2 * w2);
    const unsigned short* o1 = P1 + ((size_t)p * 32 + row) * 512 + c8;
    unsigned short* ap = attn + ((size_t)(b * 2048 + qi * 32 + row)) * 4096 + head * 512 + c8;
    unsigned short res[8];
#pragma unroll
    for (int j = 0; j < 8; ++j)
      res[j] = f2bf((bf2f(o1[j]) * w1 + bf2f(ap[j]) * w2) * inv);
    *(bf16x8*)ap = *(bf16x8*)res;
  }
}

// ---------------- output projection: out += attn @ Wo^T (split-K, fp32 atomics) ----------------
__global__ __launch_bounds__(256) void out_gemm(
    const unsigned short* __restrict__ A, const unsigned short* __restrict__ W,
    float* __restrict__ C) {
  __shared__ __align__(16) unsigned short As[128 * 32];
  __shared__ __align__(16) unsigned short Bs[128 * 32];
  const int tid = threadIdx.x;
  const int wave = tid >> 6, lane = tid & 63, quad = lane >> 4, l16 = lane & 15;
  const int m0 = blockIdx.x * 128, n0 = blockIdx.y * 128;
  const int kb = blockIdx.z * 1024;
  const int wm = (wave >> 1) * 64, wn = (wave & 1) * 64;
  floatx4 acc[4][4];
#pragma unroll
  for (int i = 0; i < 4; ++i)
#pragma unroll
    for (int j = 0; j < 4; ++j) acc[i][j] = (floatx4){0.f, 0.f, 0.f, 0.f};
  const int r0 = wave * 32;
  const int lrow = lane >> 2, lchunk = (lane & 3) * 8;
  for (int k0 = kb; k0 < kb + 1024; k0 += 32) {
    const unsigned short* ga = A + (size_t)(m0 + r0 + lrow) * 4096 + k0 + lchunk;
    const unsigned short* gb = W + (size_t)(n0 + r0 + lrow) * 4096 + k0 + lchunk;
    ldsld16(ga, As + r0 * 32);
    ldsld16(ga + (size_t)16 * 4096, As + r0 * 32 + 512);
    ldsld16(gb, Bs + r0 * 32);
    ldsld16(gb + (size_t)16 * 4096, Bs + r0 * 32 + 512);
    __syncthreads();
    bf16x8 af[4], bw[4];
#pragma unroll
    for (int i = 0; i < 4; ++i) af[i] = *(const bf16x8*)(As + (wm + i * 16 + l16) * 32 + quad * 8);
#pragma unroll
    for (int j = 0; j < 4; ++j) bw[j] = *(const bf16x8*)(Bs + (wn + j * 16 + l16) * 32 + quad * 8);
#pragma unroll
    for (int i = 0; i < 4; ++i)
#pragma unroll
      for (int j = 0; j < 4; ++j) acc[i][j] = MFMA16(af[i], bw[j], acc[i][j]);
    __syncthreads();
  }
#pragma unroll
  for (int i = 0; i < 4; ++i)
#pragma unroll
    for (int j = 0; j < 4; ++j) {
      int gn = n0 + wn + j * 16 + l16;
#pragma unroll
      for (int r = 0; r < 4; ++r) {
        int gm = m0 + wm + i * 16 + quad * 4 + r;
        unsafeAtomicAdd(&C[(size_t)gm * 1024 + gn], acc[i][j][r]);
      }
    }
}

extern "C" void kernel_launch(void* const* d_in, const int* in_sizes, int n_in,
                              void* d_out, int out_size, void* d_ws, size_t ws_size,
                              hipStream_t stream) {
  const float* x  = (const float*)d_in[0];
  const float* Wq = (const float*)d_in[1];
  const float* Wk = (const float*)d_in[2];
  const float* Wv = (const float*)d_in[3];
  const float* Wo = (const float*)d_in[4];
  float* out = (float*)d_out;
  char* ws = (char*)d_ws;
  const size_t MB = 1048576;
  unsigned short* xb    = (unsigned short*)(ws + 0 * MB);
  unsigned short* wqb   = (unsigned short*)(ws + 8 * MB);
  unsigned short* wkb   = (unsigned short*)(ws + 16 * MB);
  unsigned short* wvb   = (unsigned short*)(ws + 24 * MB);
  unsigned short* wob   = (unsigned short*)(ws + 32 * MB);
  unsigned short* Qb    = (unsigned short*)(ws + 40 * MB);
  unsigned short* Kb    = (unsigned short*)(ws + 72 * MB);
  unsigned short* Vb    = (unsigned short*)(ws + 104 * MB);  // slab [BH][64][512][32]
  unsigned short* attnb = (unsigned short*)(ws + 0 * MB);    // reuse (dead post-qkv)
  unsigned short* P1    = (unsigned short*)(ws + 136 * MB);  // 16.8 MB (split mode)
  float* ml1            = (float*)(ws + 153 * MB);           // 128 KB
  float* ml2            = (float*)(ws + 153 * MB + 131072);  // 128 KB
  const int split = (ws_size >= (size_t)160 * MB) ? 1 : 0;

  hipMemsetAsync(d_out, 0, (size_t)4096 * 1024 * 4, stream);  // out_gemm accumulates

  cast5_k<<<dim3(4096, 5), 256, 0, stream>>>(x, Wq, Wk, Wv, Wo, xb, wqb, wkb, wvb, wob);
  qkv_gemm<<<dim3(32, 32, 3), 256, 0, stream>>>(xb, wqb, wkb, wvb, Qb, Kb, Vb);
  rope_k<<<65536, 256, 0, stream>>>(Qb, Kb);
  flash_attn<<<dim3(16, split ? 96 : 64), 128, 0, stream>>>(Qb, Kb, Vb, attnb, P1, ml1, ml2, split);
  if (split) combine_k<<<512, 256, 0, stream>>>(P1, ml1, ml2, attnb);
  out_gemm<<<dim3(32, 8, 4), 256, 0, stream>>>(attnb, wob, out);
}

// Round 5
// 954.148 us; speedup vs baseline: 1.9682x; 1.9682x over previous
//
#include <hip/hip_runtime.h>

// B=2, T=2048, E=1024, H=8, D=512, HD=4096. bf16 MFMA internally.
// NOTE: every register-array loop (qf/o/sc) MUST be fully unrolled —
// partial unroll => dynamic index => scratch spill (round-4 lesson: 5.6 GB HBM).

#define DEV __device__ __forceinline__

using bf16x8  = __attribute__((ext_vector_type(8))) short;
using floatx4 = __attribute__((ext_vector_type(4))) float;

#define MFMA16(a, b, c) __builtin_amdgcn_mfma_f32_16x16x32_bf16((a), (b), (c), 0, 0, 0)

DEV unsigned short f2bf(float f) {
  union { float f; unsigned int u; } c; c.f = f;
  unsigned int u = c.u + 0x7FFFu + ((c.u >> 16) & 1u);
  return (unsigned short)(u >> 16);
}
DEV float bf2f(unsigned short h) {
  union { unsigned int u; float f; } c; c.u = ((unsigned int)h) << 16;
  return c.f;
}

// async global->LDS, 16B per lane. LDS dest = wave-uniform base + lane*16.
DEV void ldsld16(const unsigned short* g, unsigned short* l) {
  __builtin_amdgcn_global_load_lds(
      (__attribute__((address_space(1))) void*)(g),
      (__attribute__((address_space(3))) void*)(l), 16, 0, 0);
}

// ---------------- fused cast fp32 -> bf16 for all 5 tensors ----------------
__global__ void cast5_k(const float* __restrict__ x,  const float* __restrict__ wq,
                        const float* __restrict__ wk, const float* __restrict__ wv,
                        const float* __restrict__ wo,
                        unsigned short* __restrict__ xb,  unsigned short* __restrict__ wqb,
                        unsigned short* __restrict__ wkb, unsigned short* __restrict__ wvb,
                        unsigned short* __restrict__ wob) {
  const float* s; unsigned short* d;
  switch (blockIdx.y) {
    case 0: s = x;  d = xb;  break;
    case 1: s = wq; d = wqb; break;
    case 2: s = wk; d = wkb; break;
    case 3: s = wv; d = wvb; break;
    default: s = wo; d = wob; break;
  }
  int i = blockIdx.x * 256 + threadIdx.x;
  float4 v = ((const float4*)s)[i];
  uint2 o;
  o.x = (unsigned int)f2bf(v.x) | ((unsigned int)f2bf(v.y) << 16);
  o.y = (unsigned int)f2bf(v.z) | ((unsigned int)f2bf(v.w) << 16);
  ((uint2*)d)[i] = o;
}

// ---------------- QKV projection GEMM ----------------
// Q,K -> [B,H,T,D]. V -> slab layout [BH][T/32][D][32] (coalesced flash reads).
__global__ __launch_bounds__(256) void qkv_gemm(
    const unsigned short* __restrict__ X,
    const unsigned short* __restrict__ Wq, const unsigned short* __restrict__ Wk,
    const unsigned short* __restrict__ Wv,
    unsigned short* __restrict__ Qo, unsigned short* __restrict__ Ko, unsigned short* __restrict__ Vo) {
  __shared__ __align__(16) unsigned short As[128 * 32];
  __shared__ __align__(16) unsigned short Bs[128 * 32];
  const int tid = threadIdx.x;
  const int wave = tid >> 6, lane = tid & 63, quad = lane >> 4, l16 = lane & 15;
  const int m0 = blockIdx.x * 128, n0 = blockIdx.y * 128;
  const int z = blockIdx.z;
  const unsigned short* W = (z == 0) ? Wq : (z == 1) ? Wk : Wv;
  const int wm = (wave >> 1) * 64, wn = (wave & 1) * 64;
  floatx4 acc[4][4];
#pragma unroll
  for (int i = 0; i < 4; ++i)
#pragma unroll
    for (int j = 0; j < 4; ++j) acc[i][j] = (floatx4){0.f, 0.f, 0.f, 0.f};

  const int r0 = wave * 32;
  const int lrow = lane >> 2, lchunk = (lane & 3) * 8;
  for (int k0 = 0; k0 < 1024; k0 += 32) {
    const unsigned short* ga = X + (size_t)(m0 + r0 + lrow) * 1024 + k0 + lchunk;
    const unsigned short* gb = W + (size_t)(n0 + r0 + lrow) * 1024 + k0 + lchunk;
    ldsld16(ga, As + r0 * 32);
    ldsld16(ga + (size_t)16 * 1024, As + r0 * 32 + 512);
    ldsld16(gb, Bs + r0 * 32);
    ldsld16(gb + (size_t)16 * 1024, Bs + r0 * 32 + 512);
    __syncthreads();
    bf16x8 af[4], bw[4];
#pragma unroll
    for (int i = 0; i < 4; ++i) af[i] = *(const bf16x8*)(As + (wm + i * 16 + l16) * 32 + quad * 8);
#pragma unroll
    for (int j = 0; j < 4; ++j) bw[j] = *(const bf16x8*)(Bs + (wn + j * 16 + l16) * 32 + quad * 8);
#pragma unroll
    for (int i = 0; i < 4; ++i)
#pragma unroll
      for (int j = 0; j < 4; ++j) acc[i][j] = MFMA16(af[i], bw[j], acc[i][j]);
    __syncthreads();
  }
#pragma unroll
  for (int i = 0; i < 4; ++i)
#pragma unroll
    for (int j = 0; j < 4; ++j) {
      int gn = n0 + wn + j * 16 + l16;
      int h = gn >> 9, d = gn & 511;
      int gm0 = m0 + wm + i * 16 + quad * 4;
      int b = gm0 >> 11, t0 = gm0 & 2047;
      if (z == 2) {
        unsigned short pk[4];
#pragma unroll
        for (int r = 0; r < 4; ++r) pk[r] = f2bf(acc[i][j][r]);
        size_t off = ((size_t)((b * 8 + h) * 64 + (t0 >> 5))) * 16384 + (size_t)d * 32 + (t0 & 31);
        *(uint2*)(Vo + off) = *(uint2*)pk;   // packed 8B slab write
      } else {
        unsigned short* P = (z == 0) ? Qo : Ko;
        size_t base = ((size_t)((b * 8 + h) * 2048 + t0)) * 512 + d;
#pragma unroll
        for (int r = 0; r < 4; ++r) P[base + (size_t)r * 512] = f2bf(acc[i][j][r]);
      }
    }
}

// ---------------- RoPE (Q,K only; V slab untouched) ----------------
__global__ void rope_k(unsigned short* __restrict__ Q, unsigned short* __restrict__ K) {
  int idx = blockIdx.x * 256 + threadIdx.x;
  unsigned short* P = (idx & 8388608) ? K : Q;
  int r = idx & 8388607;
  int row = r >> 8;
  int i = r & 255;
  int t = row & 2047;
  size_t base = (size_t)row * 512;
  float x1 = bf2f(P[base + i]);
  float x2 = bf2f(P[base + i + 256]);
  float freq = expf(-(float)i * 0.03597789207803197f);
  float ang = (float)t * freq;
  float sv, cv;
  sincosf(ang, &sv, &cv);
  P[base + i]       = f2bf(x1 * cv - x2 * sv);
  P[base + i + 256] = f2bf(x1 * sv + x2 * cv);
}

// ---------------- flash attention v5: barrier-free, fully unrolled ----------------
// WG = 128 threads = 2 independent waves. Wave owns 16 q-rows x full 512 d.
// K,V fragments read directly from global (L2/L3); only LDS is a per-wave
// private P tile (stride-72 padding). NO __syncthreads anywhere.
// grid (16 bh, jobs). q-tile 32 rows; s-tile 64; qi>=32 split into 2 s-chunks.
__global__ __launch_bounds__(128, 2) void flash_attn(
    const unsigned short* __restrict__ Q, const unsigned short* __restrict__ K,
    const unsigned short* __restrict__ Vslab, unsigned short* __restrict__ attn,
    unsigned short* __restrict__ P1, float* __restrict__ ml1, float* __restrict__ ml2,
    int split) {
  __shared__ __align__(16) unsigned short Ps[2 * 16 * 72];  // per-wave [16][72-pad]
  const int tid = threadIdx.x;
  const int wave = tid >> 6, lane = tid & 63, quad = lane >> 4, l16 = lane & 15;
  const int bh = blockIdx.x, b = bh >> 3, head = bh & 7;
  const int y = blockIdx.y;
  int qi, st0, stN, om;  // om: 0 direct, 1 chunk0->P1, 2 chunk1->attn unnormalized
  if (split) {
    if (y < 64) {
      qi = 63 - (y >> 1);
      int tot = (qi >> 1) + 1, mid = tot >> 1;
      if ((y & 1) == 0) { st0 = 0;   stN = mid; om = 1; }
      else              { st0 = mid; stN = tot; om = 2; }
    } else { qi = 95 - y; st0 = 0; stN = (qi >> 1) + 1; om = 0; }
  } else { qi = 63 - y; st0 = 0; stN = (qi >> 1) + 1; om = 0; }

  const size_t bhoff = (size_t)bh << 20;
  const unsigned short* Qp = Q + bhoff;
  const unsigned short* Kp = K + bhoff;
  const unsigned short* Vp = Vslab + bhoff;
  const int qb = qi * 32;
  const int qw0 = qb + wave * 16;         // wave's first q-row

  // Q fragments: 16 k-steps (A-frag: m=l16, k=quad*8+j)
  bf16x8 qf[16];
  {
    const unsigned short* qrow = Qp + (size_t)(qw0 + l16) * 512 + quad * 8;
#pragma unroll
    for (int ks = 0; ks < 16; ++ks) qf[ks] = *(const bf16x8*)(qrow + ks * 32);
  }
  floatx4 o[32];
#pragma unroll
  for (int n = 0; n < 32; ++n) o[n] = (floatx4){0.f, 0.f, 0.f, 0.f};
  float m_[4], l_[4];
#pragma unroll
  for (int r = 0; r < 4; ++r) { m_[r] = -3.0e38f; l_[r] = 0.f; }

  unsigned short* psw = Ps + wave * 1152;  // 16 rows x 72

  for (int st = st0; st < stN; ++st) {
    const int s0 = st * 64;
    // ---- QK: S[16q][64s] over full 512 d, K direct from global ----
    floatx4 sc[4];
#pragma unroll
    for (int c = 0; c < 4; ++c) sc[c] = (floatx4){0.f, 0.f, 0.f, 0.f};
    const unsigned short* kr0 = Kp + (size_t)(s0 + l16) * 512 + quad * 8;
#pragma unroll
    for (int ks = 0; ks < 16; ++ks) {
      bf16x8 k0 = *(const bf16x8*)(kr0 + ks * 32);
      bf16x8 k1 = *(const bf16x8*)(kr0 + 16 * 512 + ks * 32);
      bf16x8 k2 = *(const bf16x8*)(kr0 + 32 * 512 + ks * 32);
      bf16x8 k3 = *(const bf16x8*)(kr0 + 48 * 512 + ks * 32);
      sc[0] = MFMA16(qf[ks], k0, sc[0]);
      sc[1] = MFMA16(qf[ks], k1, sc[1]);
      sc[2] = MFMA16(qf[ks], k2, sc[2]);
      sc[3] = MFMA16(qf[ks], k3, sc[3]);
    }
    // ---- softmax over 64 cols (rows quad*4+r, col block c at s0+c*16+l16) ----
    const float scale = 0.04419417382415922f;  // 1/sqrt(512)
    const bool need_mask = (s0 + 63 > qw0);    // wave-uniform: only diagonal tile
    float mr[4];
#pragma unroll
    for (int r = 0; r < 4; ++r) mr[r] = -3.0e38f;
#pragma unroll
    for (int c = 0; c < 4; ++c) {
      int scol = s0 + c * 16 + l16;
#pragma unroll
      for (int r = 0; r < 4; ++r) {
        float a = sc[c][r] * scale;
        if (need_mask && scol > qw0 + quad * 4 + r) a = -3.0e38f;
        sc[c][r] = a;
        mr[r] = fmaxf(mr[r], a);
      }
    }
#pragma unroll
    for (int off = 1; off < 16; off <<= 1)
#pragma unroll
      for (int r = 0; r < 4; ++r) mr[r] = fmaxf(mr[r], __shfl_xor(mr[r], off, 64));
    float alpha[4], rs[4];
#pragma unroll
    for (int r = 0; r < 4; ++r) {
      float mn = fmaxf(m_[r], mr[r]);
      alpha[r] = __expf(m_[r] - mn);
      m_[r] = mn;
      rs[r] = 0.f;
    }
#pragma unroll
    for (int c = 0; c < 4; ++c)
#pragma unroll
      for (int r = 0; r < 4; ++r) {
        float p = __expf(sc[c][r] - m_[r]);
        rs[r] += p;
        psw[(quad * 4 + r) * 72 + c * 16 + l16] = f2bf(p);
      }
#pragma unroll
    for (int off = 1; off < 16; off <<= 1)
#pragma unroll
      for (int r = 0; r < 4; ++r) rs[r] += __shfl_xor(rs[r], off, 64);
#pragma unroll
    for (int r = 0; r < 4; ++r) l_[r] = l_[r] * alpha[r] + rs[r];
    // skip O-rescale when no row max moved
    if (__any(alpha[0] + alpha[1] + alpha[2] + alpha[3] < 4.0f)) {
#pragma unroll
      for (int n = 0; n < 32; ++n)
#pragma unroll
        for (int r = 0; r < 4; ++r) o[n][r] *= alpha[r];
    }
    // ---- PV: O[16][512] += P[16][64] * V[64][512], V direct from slab ----
    bf16x8 pf0 = *(const bf16x8*)(psw + l16 * 72 + quad * 8);        // s 0..31
    bf16x8 pf1 = *(const bf16x8*)(psw + l16 * 72 + 32 + quad * 8);   // s 32..63
    const unsigned short* vb0 = Vp + (size_t)(2 * st) * 16384 + (size_t)l16 * 32 + quad * 8;
#pragma unroll
    for (int nt = 0; nt < 32; ++nt) {
      bf16x8 vf = *(const bf16x8*)(vb0 + (size_t)nt * 512);
      o[nt] = MFMA16(pf0, vf, o[nt]);
    }
    const unsigned short* vb1 = vb0 + 16384;
#pragma unroll
    for (int nt = 0; nt < 32; ++nt) {
      bf16x8 vf = *(const bf16x8*)(vb1 + (size_t)nt * 512);
      o[nt] = MFMA16(pf1, vf, o[nt]);
    }
  }
  // ---- outputs ----
  const int rbase = wave * 16 + quad * 4;  // row within 32-row q-tile, +r
  const int p1i = bh * 32 + (qi - 32);
  if (om == 1) {
    unsigned short* prow = P1 + ((size_t)p1i * 32 + rbase) * 512 + l16;
#pragma unroll
    for (int nt = 0; nt < 32; ++nt)
#pragma unroll
      for (int r = 0; r < 4; ++r)
        prow[(size_t)r * 512 + nt * 16] = f2bf(o[nt][r]);   // unnormalized
  } else {
    unsigned short* arow =
        attn + ((size_t)(b * 2048 + qb + rbase)) * 4096 + head * 512 + l16;
    if (om == 0) {
      float inv[4];
#pragma unroll
      for (int r = 0; r < 4; ++r) inv[r] = 1.0f / l_[r];
#pragma unroll
      for (int nt = 0; nt < 32; ++nt)
#pragma unroll
        for (int r = 0; r < 4; ++r)
          arow[(size_t)r * 4096 + nt * 16] = f2bf(o[nt][r] * inv[r]);
    } else {
#pragma unroll
      for (int nt = 0; nt < 32; ++nt)
#pragma unroll
        for (int r = 0; r < 4; ++r)
          arow[(size_t)r * 4096 + nt * 16] = f2bf(o[nt][r]);  // unnormalized
    }
  }
  if (om != 0 && l16 == 0) {
    float* ml = (om == 1) ? ml1 : ml2;
#pragma unroll
    for (int r = 0; r < 4; ++r) {
      ml[(size_t)p1i * 64 + (rbase + r) * 2]     = m_[r];
      ml[(size_t)p1i * 64 + (rbase + r) * 2 + 1] = l_[r];
    }
  }
}

// ---------------- combine split partials (qi>=32) ----------------
__global__ void combine_k(const unsigned short* __restrict__ P1,
                          const float* __restrict__ ml1, const float* __restrict__ ml2,
                          unsigned short* __restrict__ attn) {
  const int p = blockIdx.x;  // [0,512)
  const int bh = p >> 5, qi = 32 + (p & 31), b = bh >> 3, head = bh & 7;
  const int tid = threadIdx.x;
#pragma unroll
  for (int it = 0; it < 8; ++it) {
    int idx = it * 256 + tid;        // 32 rows * 64 chunks
    int row = idx >> 6, c8 = (idx & 63) * 8;
    float m1 = ml1[(size_t)p * 64 + row * 2], l1 = ml1[(size_t)p * 64 + row * 2 + 1];
    float m2 = ml2[(size_t)p * 64 + row * 2], l2 = ml2[(size_t)p * 64 + row * 2 + 1];
    float M = fmaxf(m1, m2);
    float w1 = __expf(m1 - M), w2 = __expf(m2 - M);
    float inv = 1.0f / (l1 * w1 + l2 * w2);
    const unsigned short* o1 = P1 + ((size_t)p * 32 + row) * 512 + c8;
    unsigned short* ap = attn + ((size_t)(b * 2048 + qi * 32 + row)) * 4096 + head * 512 + c8;
    unsigned short res[8];
#pragma unroll
    for (int j = 0; j < 8; ++j)
      res[j] = f2bf((bf2f(o1[j]) * w1 + bf2f(ap[j]) * w2) * inv);
    *(bf16x8*)ap = *(bf16x8*)res;
  }
}

// ---------------- output projection: out += attn @ Wo^T (split-K, fp32 atomics) ----------------
__global__ __launch_bounds__(256) void out_gemm(
    const unsigned short* __restrict__ A, const unsigned short* __restrict__ W,
    float* __restrict__ C) {
  __shared__ __align__(16) unsigned short As[128 * 32];
  __shared__ __align__(16) unsigned short Bs[128 * 32];
  const int tid = threadIdx.x;
  const int wave = tid >> 6, lane = tid & 63, quad = lane >> 4, l16 = lane & 15;
  const int m0 = blockIdx.x * 128, n0 = blockIdx.y * 128;
  const int kb = blockIdx.z * 1024;
  const int wm = (wave >> 1) * 64, wn = (wave & 1) * 64;
  floatx4 acc[4][4];
#pragma unroll
  for (int i = 0; i < 4; ++i)
#pragma unroll
    for (int j = 0; j < 4; ++j) acc[i][j] = (floatx4){0.f, 0.f, 0.f, 0.f};
  const int r0 = wave * 32;
  const int lrow = lane >> 2, lchunk = (lane & 3) * 8;
  for (int k0 = kb; k0 < kb + 1024; k0 += 32) {
    const unsigned short* ga = A + (size_t)(m0 + r0 + lrow) * 4096 + k0 + lchunk;
    const unsigned short* gb = W + (size_t)(n0 + r0 + lrow) * 4096 + k0 + lchunk;
    ldsld16(ga, As + r0 * 32);
    ldsld16(ga + (size_t)16 * 4096, As + r0 * 32 + 512);
    ldsld16(gb, Bs + r0 * 32);
    ldsld16(gb + (size_t)16 * 4096, Bs + r0 * 32 + 512);
    __syncthreads();
    bf16x8 af[4], bw[4];
#pragma unroll
    for (int i = 0; i < 4; ++i) af[i] = *(const bf16x8*)(As + (wm + i * 16 + l16) * 32 + quad * 8);
#pragma unroll
    for (int j = 0; j < 4; ++j) bw[j] = *(const bf16x8*)(Bs + (wn + j * 16 + l16) * 32 + quad * 8);
#pragma unroll
    for (int i = 0; i < 4; ++i)
#pragma unroll
      for (int j = 0; j < 4; ++j) acc[i][j] = MFMA16(af[i], bw[j], acc[i][j]);
    __syncthreads();
  }
#pragma unroll
  for (int i = 0; i < 4; ++i)
#pragma unroll
    for (int j = 0; j < 4; ++j) {
      int gn = n0 + wn + j * 16 + l16;
#pragma unroll
      for (int r = 0; r < 4; ++r) {
        int gm = m0 + wm + i * 16 + quad * 4 + r;
        unsafeAtomicAdd(&C[(size_t)gm * 1024 + gn], acc[i][j][r]);
      }
    }
}

extern "C" void kernel_launch(void* const* d_in, const int* in_sizes, int n_in,
                              void* d_out, int out_size, void* d_ws, size_t ws_size,
                              hipStream_t stream) {
  const float* x  = (const float*)d_in[0];
  const float* Wq = (const float*)d_in[1];
  const float* Wk = (const float*)d_in[2];
  const float* Wv = (const float*)d_in[3];
  const float* Wo = (const float*)d_in[4];
  float* out = (float*)d_out;
  char* ws = (char*)d_ws;
  const size_t MB = 1048576;
  unsigned short* xb    = (unsigned short*)(ws + 0 * MB);
  unsigned short* wqb   = (unsigned short*)(ws + 8 * MB);
  unsigned short* wkb   = (unsigned short*)(ws + 16 * MB);
  unsigned short* wvb   = (unsigned short*)(ws + 24 * MB);
  unsigned short* wob   = (unsigned short*)(ws + 32 * MB);
  unsigned short* Qb    = (unsigned short*)(ws + 40 * MB);
  unsigned short* Kb    = (unsigned short*)(ws + 72 * MB);
  unsigned short* Vb    = (unsigned short*)(ws + 104 * MB);  // slab [BH][64][512][32]
  unsigned short* attnb = (unsigned short*)(ws + 0 * MB);    // reuse (dead post-qkv)
  unsigned short* P1    = (unsigned short*)(ws + 136 * MB);  // 16.8 MB (split mode)
  float* ml1            = (float*)(ws + 153 * MB);           // 128 KB
  float* ml2            = (float*)(ws + 153 * MB + 131072);  // 128 KB
  const int split = (ws_size >= (size_t)160 * MB) ? 1 : 0;

  hipMemsetAsync(d_out, 0, (size_t)4096 * 1024 * 4, stream);  // out_gemm accumulates

  cast5_k<<<dim3(4096, 5), 256, 0, stream>>>(x, Wq, Wk, Wv, Wo, xb, wqb, wkb, wvb, wob);
  qkv_gemm<<<dim3(32, 32, 3), 256, 0, stream>>>(xb, wqb, wkb, wvb, Qb, Kb, Vb);
  rope_k<<<65536, 256, 0, stream>>>(Qb, Kb);
  flash_attn<<<dim3(16, split ? 96 : 64), 128, 0, stream>>>(Qb, Kb, Vb, attnb, P1, ml1, ml2, split);
  if (split) combine_k<<<512, 256, 0, stream>>>(P1, ml1, ml2, attnb);
  out_gemm<<<dim3(32, 8, 4), 256, 0, stream>>>(attnb, wob, out);
}

// Round 6
// 702.241 us; speedup vs baseline: 2.6742x; 1.3587x over previous
//
#include <hip/hip_runtime.h>

// B=2, T=2048, E=1024, H=8, D=512, HD=4096. bf16 MFMA internally.
// Lessons encoded: (R4) register-array loops must be FULLY unrolled or they
// spill; (R5) no cross-wave K/V reuse => latency death; (R2) LDS sharing works
// but K stride 264 gave 8-way conflicts and per-lane V staging burned VALU.
// v6: K/V pre-padded in global (K rows 536 shorts = 268 dw = 12 mod 32 -> 2-way;
// V rows 40 shorts = 20 dw -> 2-way), staged via global_load_lds DMA, 2 barriers.

#define DEV __device__ __forceinline__

using bf16x8  = __attribute__((ext_vector_type(8))) short;
using floatx4 = __attribute__((ext_vector_type(4))) float;

#define MFMA16(a, b, c) __builtin_amdgcn_mfma_f32_16x16x32_bf16((a), (b), (c), 0, 0, 0)

// K padded tiles: [bh][64][32][536] shorts
#define KT_BH 1097728
#define KT_TILE 17152
#define KT_ROW 536
// V padded slab: [bh][64][512][40] shorts
#define VT_BH 1310720
#define VT_TILE 20480

DEV unsigned short f2bf(float f) {
  union { float f; unsigned int u; } c; c.f = f;
  unsigned int u = c.u + 0x7FFFu + ((c.u >> 16) & 1u);
  return (unsigned short)(u >> 16);
}
DEV float bf2f(unsigned short h) {
  union { unsigned int u; float f; } c; c.u = ((unsigned int)h) << 16;
  return c.f;
}

// async global->LDS, 16B/lane. g is PER-LANE address; l is wave-uniform base.
DEV void ldsld16(const unsigned short* g, unsigned short* l) {
  __builtin_amdgcn_global_load_lds(
      (__attribute__((address_space(1))) void*)(g),
      (__attribute__((address_space(3))) void*)(l), 16, 0, 0);
}

// ---------------- cast fp32 -> bf16 (x, Wq, Wk, Wv) ----------------
__global__ void cast4_k(const float* __restrict__ x,  const float* __restrict__ wq,
                        const float* __restrict__ wk, const float* __restrict__ wv,
                        unsigned short* __restrict__ xb,  unsigned short* __restrict__ wqb,
                        unsigned short* __restrict__ wkb, unsigned short* __restrict__ wvb) {
  const float* s; unsigned short* d;
  switch (blockIdx.y) {
    case 0: s = x;  d = xb;  break;
    case 1: s = wq; d = wqb; break;
    case 2: s = wk; d = wkb; break;
    default: s = wv; d = wvb; break;
  }
  int i = blockIdx.x * 256 + threadIdx.x;
  float4 v = ((const float4*)s)[i];
  uint2 o;
  o.x = (unsigned int)f2bf(v.x) | ((unsigned int)f2bf(v.y) << 16);
  o.y = (unsigned int)f2bf(v.z) | ((unsigned int)f2bf(v.w) << 16);
  ((uint2*)d)[i] = o;
}

__global__ void cast1_k(const float* __restrict__ s, unsigned short* __restrict__ d) {
  int i = blockIdx.x * 256 + threadIdx.x;
  float4 v = ((const float4*)s)[i];
  uint2 o;
  o.x = (unsigned int)f2bf(v.x) | ((unsigned int)f2bf(v.y) << 16);
  o.y = (unsigned int)f2bf(v.z) | ((unsigned int)f2bf(v.w) << 16);
  ((uint2*)d)[i] = o;
}

// ---------------- QKV projection GEMM ----------------
// Q -> [B,H,T,D]; K -> padded tiles [bh][t/32][32][536]; V -> padded slab
// [bh][t/32][512][40]  (both DMA-ready for flash).
__global__ __launch_bounds__(256) void qkv_gemm(
    const unsigned short* __restrict__ X,
    const unsigned short* __restrict__ Wq, const unsigned short* __restrict__ Wk,
    const unsigned short* __restrict__ Wv,
    unsigned short* __restrict__ Qo, unsigned short* __restrict__ Ko, unsigned short* __restrict__ Vo) {
  __shared__ __align__(16) unsigned short As[128 * 32];
  __shared__ __align__(16) unsigned short Bs[128 * 32];
  const int tid = threadIdx.x;
  const int wave = tid >> 6, lane = tid & 63, quad = lane >> 4, l16 = lane & 15;
  const int m0 = blockIdx.x * 128, n0 = blockIdx.y * 128;
  const int z = blockIdx.z;
  const unsigned short* W = (z == 0) ? Wq : (z == 1) ? Wk : Wv;
  const int wm = (wave >> 1) * 64, wn = (wave & 1) * 64;
  floatx4 acc[4][4];
#pragma unroll
  for (int i = 0; i < 4; ++i)
#pragma unroll
    for (int j = 0; j < 4; ++j) acc[i][j] = (floatx4){0.f, 0.f, 0.f, 0.f};

  const int r0 = wave * 32;
  const int lrow = lane >> 2, lchunk = (lane & 3) * 8;
  for (int k0 = 0; k0 < 1024; k0 += 32) {
    const unsigned short* ga = X + (size_t)(m0 + r0 + lrow) * 1024 + k0 + lchunk;
    const unsigned short* gb = W + (size_t)(n0 + r0 + lrow) * 1024 + k0 + lchunk;
    ldsld16(ga, As + r0 * 32);
    ldsld16(ga + (size_t)16 * 1024, As + r0 * 32 + 512);
    ldsld16(gb, Bs + r0 * 32);
    ldsld16(gb + (size_t)16 * 1024, Bs + r0 * 32 + 512);
    __syncthreads();
    bf16x8 af[4], bw[4];
#pragma unroll
    for (int i = 0; i < 4; ++i) af[i] = *(const bf16x8*)(As + (wm + i * 16 + l16) * 32 + quad * 8);
#pragma unroll
    for (int j = 0; j < 4; ++j) bw[j] = *(const bf16x8*)(Bs + (wn + j * 16 + l16) * 32 + quad * 8);
#pragma unroll
    for (int i = 0; i < 4; ++i)
#pragma unroll
      for (int j = 0; j < 4; ++j) acc[i][j] = MFMA16(af[i], bw[j], acc[i][j]);
    __syncthreads();
  }
#pragma unroll
  for (int i = 0; i < 4; ++i)
#pragma unroll
    for (int j = 0; j < 4; ++j) {
      int gn = n0 + wn + j * 16 + l16;
      int h = gn >> 9, d = gn & 511;
      int gm0 = m0 + wm + i * 16 + quad * 4;
      int b = gm0 >> 11, t0 = gm0 & 2047;   // t0&31 in {0,4,...,28}
      int bh = b * 8 + h;
      if (z == 2) {
        unsigned short pk[4];
#pragma unroll
        for (int r = 0; r < 4; ++r) pk[r] = f2bf(acc[i][j][r]);
        size_t off = (size_t)bh * VT_BH + (t0 >> 5) * VT_TILE + (size_t)d * 40 + (t0 & 31);
        *(uint2*)(Vo + off) = *(uint2*)pk;   // packed 8B, 8B-aligned
      } else if (z == 1) {
        size_t off = (size_t)bh * KT_BH + (t0 >> 5) * KT_TILE + (size_t)(t0 & 31) * KT_ROW + d;
#pragma unroll
        for (int r = 0; r < 4; ++r) Ko[off + (size_t)r * KT_ROW] = f2bf(acc[i][j][r]);
      } else {
        size_t base = ((size_t)(bh * 2048 + t0)) * 512 + d;
#pragma unroll
        for (int r = 0; r < 4; ++r) Qo[base + (size_t)r * 512] = f2bf(acc[i][j][r]);
      }
    }
}

// ---------------- RoPE (Q in place; K in padded tile layout) ----------------
__global__ void rope_k(unsigned short* __restrict__ Q, unsigned short* __restrict__ Kt) {
  int idx = blockIdx.x * 256 + threadIdx.x;
  int r = idx & 8388607;
  int row = r >> 8;                       // bh*2048 + t
  int i = r & 255;
  int t = row & 2047;
  unsigned short* P;
  size_t base;
  if (idx & 8388608) {
    int bh = row >> 11;
    base = (size_t)bh * KT_BH + (t >> 5) * KT_TILE + (size_t)(t & 31) * KT_ROW;
    P = Kt;
  } else {
    base = (size_t)row * 512;
    P = Q;
  }
  float x1 = bf2f(P[base + i]);
  float x2 = bf2f(P[base + i + 256]);
  float freq = expf(-(float)i * 0.03597789207803197f);  // ln(10000)/256
  float ang = (float)t * freq;
  float sv, cv;
  sincosf(ang, &sv, &cv);
  P[base + i]       = f2bf(x1 * cv - x2 * sv);
  P[base + i + 256] = f2bf(x1 * sv + x2 * cv);
}

// ---------------- flash attention v6: shared LDS tiles, DMA-staged ----------------
// WG = 4 waves; q-tile 64 (wave owns 16 q x full 512 d); s-tile 32.
// K tile [32][536] + V tile [512][40] staged once per step via global_load_lds
// from pre-padded global layouts; 4-way wave reuse; 2 barriers/step.
__global__ __launch_bounds__(256, 2) void flash_attn(
    const unsigned short* __restrict__ Q, const unsigned short* __restrict__ Kt,
    const unsigned short* __restrict__ Vt, unsigned short* __restrict__ attn,
    unsigned short* __restrict__ P1, float* __restrict__ ml1, float* __restrict__ ml2,
    int split) {
  __shared__ __align__(16) unsigned short Ks[32 * 536];   // 34304 B
  __shared__ __align__(16) unsigned short Vs[512 * 40];   // 40960 B
  __shared__ __align__(16) unsigned short Ps[4 * 16 * 40];  // 5120 B, per-wave
  const int tid = threadIdx.x;
  const int wave = tid >> 6, lane = tid & 63, quad = lane >> 4, l16 = lane & 15;
  const int bh = blockIdx.x, b = bh >> 3, head = bh & 7;
  const int y = blockIdx.y;
  int qi, st0, stN, om;  // om: 0 direct, 1 chunk0->P1, 2 chunk1->attn unnormalized
  if (split) {
    if (y < 16)      { qi = 31 - y; st0 = 0;  stN = 32;         om = 1; }
    else if (y < 32) { qi = 47 - y; st0 = 32; stN = 2 * qi + 2; om = 2; }
    else             { qi = 47 - y; st0 = 0;  stN = 2 * qi + 2; om = 0; }
  } else { qi = (y < 16) ? (31 - y) : (y - 16); st0 = 0; stN = 2 * qi + 2; om = 0; }

  const unsigned short* Qp = Q + ((size_t)bh << 20);
  const unsigned short* Kp = Kt + (size_t)bh * KT_BH;
  const unsigned short* Vp = Vt + (size_t)bh * VT_BH;
  const int qb = qi * 64;

  // Q fragments (A-frag: m=l16, k=quad*8+j), 16 k-steps over 512 d
  bf16x8 qf[16];
  {
    const unsigned short* qrow = Qp + (size_t)(qb + wave * 16 + l16) * 512 + quad * 8;
#pragma unroll
    for (int ks = 0; ks < 16; ++ks) qf[ks] = *(const bf16x8*)(qrow + ks * 32);
  }
  floatx4 o[32];
#pragma unroll
  for (int n = 0; n < 32; ++n) o[n] = (floatx4){0.f, 0.f, 0.f, 0.f};
  float m_[4], l_[4];
#pragma unroll
  for (int r = 0; r < 4; ++r) { m_[r] = -3.0e38f; l_[r] = 0.f; }

  unsigned short* psw = Ps + wave * 640;  // [16][40]

  // ---- DMA helpers (K: 2144 chunks, wave w covers [w*536, w*536+536);
  //      V: 2560 chunks, wave w covers [w*640, w*640+640)) ----
  {
    const unsigned short* gk = Kp + (size_t)st0 * KT_TILE;
    const unsigned short* gv = Vp + (size_t)st0 * VT_TILE;
#pragma unroll
    for (int j = 0; j < 9; ++j) {
      int c0 = wave * 536 + j * 64;
      if (j < 8 || lane < 24) ldsld16(gk + (size_t)(c0 + lane) * 8, Ks + c0 * 8);
    }
#pragma unroll
    for (int j = 0; j < 10; ++j) {
      int c0 = wave * 640 + j * 64;
      ldsld16(gv + (size_t)(c0 + lane) * 8, Vs + c0 * 8);
    }
  }

  for (int st = st0; st < stN; ++st) {
    __syncthreads();  // DMA drained: Ks/Vs valid
    const int s0 = st * 32;
    // ---- QK: S[16q][32s] over 512 d from shared K tile ----
    floatx4 sc0 = (floatx4){0.f, 0.f, 0.f, 0.f}, sc1 = sc0;
#pragma unroll
    for (int ks = 0; ks < 16; ++ks) {
      bf16x8 k0 = *(const bf16x8*)(Ks + (size_t)l16 * 536 + ks * 32 + quad * 8);
      bf16x8 k1 = *(const bf16x8*)(Ks + (size_t)(16 + l16) * 536 + ks * 32 + quad * 8);
      sc0 = MFMA16(qf[ks], k0, sc0);
      sc1 = MFMA16(qf[ks], k1, sc1);
    }
    // ---- online softmax (rows qb+wave*16+quad*4+r; cols s0+l16, s0+16+l16) ----
    const float scale = 0.04419417382415922f;  // 1/sqrt(512)
    const int qrow0 = qb + wave * 16 + quad * 4;
    float pv0[4], pv1[4], mr[4];
#pragma unroll
    for (int r = 0; r < 4; ++r) {
      float a0 = sc0[r] * scale, a1 = sc1[r] * scale;
      if (s0 + l16 > qrow0 + r) a0 = -3.0e38f;
      if (s0 + 16 + l16 > qrow0 + r) a1 = -3.0e38f;
      pv0[r] = a0; pv1[r] = a1;
      mr[r] = fmaxf(a0, a1);
    }
#pragma unroll
    for (int off = 1; off < 16; off <<= 1)
#pragma unroll
      for (int r = 0; r < 4; ++r) mr[r] = fmaxf(mr[r], __shfl_xor(mr[r], off, 64));
    float alpha[4], rs[4];
#pragma unroll
    for (int r = 0; r < 4; ++r) {
      float mn = fmaxf(m_[r], mr[r]);
      alpha[r] = __expf(m_[r] - mn);
      m_[r] = mn;
      float p0 = __expf(pv0[r] - mn);
      float p1 = __expf(pv1[r] - mn);
      rs[r] = p0 + p1;
      psw[(quad * 4 + r) * 40 + l16] = f2bf(p0);
      psw[(quad * 4 + r) * 40 + 16 + l16] = f2bf(p1);
    }
#pragma unroll
    for (int off = 1; off < 16; off <<= 1)
#pragma unroll
      for (int r = 0; r < 4; ++r) rs[r] += __shfl_xor(rs[r], off, 64);
#pragma unroll
    for (int r = 0; r < 4; ++r) l_[r] = l_[r] * alpha[r] + rs[r];
    if (__any(alpha[0] + alpha[1] + alpha[2] + alpha[3] < 4.0f)) {
#pragma unroll
      for (int n = 0; n < 32; ++n)
#pragma unroll
        for (int r = 0; r < 4; ++r) o[n][r] *= alpha[r];
    }
    // ---- PV: O[16][512] += P[16][32] * V[32][512] from shared V tile ----
    bf16x8 pf = *(const bf16x8*)(psw + (size_t)l16 * 40 + quad * 8);  // A-frag of P
#pragma unroll
    for (int nt = 0; nt < 32; ++nt) {
      bf16x8 vf = *(const bf16x8*)(Vs + (size_t)(nt * 16 + l16) * 40 + quad * 8);
      o[nt] = MFMA16(pf, vf, o[nt]);
    }
    __syncthreads();  // all waves done reading Ks/Vs
    if (st + 1 < stN) {
      const unsigned short* gk = Kp + (size_t)(st + 1) * KT_TILE;
      const unsigned short* gv = Vp + (size_t)(st + 1) * VT_TILE;
#pragma unroll
      for (int j = 0; j < 9; ++j) {
        int c0 = wave * 536 + j * 64;
        if (j < 8 || lane < 24) ldsld16(gk + (size_t)(c0 + lane) * 8, Ks + c0 * 8);
      }
#pragma unroll
      for (int j = 0; j < 10; ++j) {
        int c0 = wave * 640 + j * 64;
        ldsld16(gv + (size_t)(c0 + lane) * 8, Vs + c0 * 8);
      }
    }
  }
  // ---- outputs ----
  const int rowi = wave * 16 + quad * 4;  // +r
  if (om == 0) {
    float inv[4];
#pragma unroll
    for (int r = 0; r < 4; ++r) inv[r] = 1.0f / l_[r];
    unsigned short* arow = attn + ((size_t)(b * 2048 + qb + rowi)) * 4096 + head * 512 + l16;
#pragma unroll
    for (int nt = 0; nt < 32; ++nt)
#pragma unroll
      for (int r = 0; r < 4; ++r)
        arow[(size_t)r * 4096 + nt * 16] = f2bf(o[nt][r] * inv[r]);
  } else {
    const int p = bh * 16 + (qi - 16);
    float* ml = (om == 1) ? ml1 : ml2;
    if (l16 == 0) {
#pragma unroll
      for (int r = 0; r < 4; ++r) {
        ml[(size_t)p * 128 + (rowi + r) * 2]     = m_[r];
        ml[(size_t)p * 128 + (rowi + r) * 2 + 1] = l_[r];
      }
    }
    if (om == 1) {
      unsigned short* prow = P1 + ((size_t)p * 64 + rowi) * 512 + l16;
#pragma unroll
      for (int nt = 0; nt < 32; ++nt)
#pragma unroll
        for (int r = 0; r < 4; ++r)
          prow[(size_t)r * 512 + nt * 16] = f2bf(o[nt][r]);   // unnormalized
    } else {
      unsigned short* arow = attn + ((size_t)(b * 2048 + qb + rowi)) * 4096 + head * 512 + l16;
#pragma unroll
      for (int nt = 0; nt < 32; ++nt)
#pragma unroll
        for (int r = 0; r < 4; ++r)
          arow[(size_t)r * 4096 + nt * 16] = f2bf(o[nt][r]);  // unnormalized
    }
  }
}

// ---------------- combine split partials (qi>=16) ----------------
__global__ void combine_k(const unsigned short* __restrict__ P1,
                          const float* __restrict__ ml1, const float* __restrict__ ml2,
                          unsigned short* __restrict__ attn) {
  const int p = blockIdx.x;  // [0,256)
  const int bh = p >> 4, b = bh >> 3, head = bh & 7, qi = 16 + (p & 15);
  const int tid = threadIdx.x;
#pragma unroll
  for (int it = 0; it < 16; ++it) {
    int idx = it * 256 + tid;        // 64 rows * 64 chunks
    int row = idx >> 6, c8 = (idx & 63) * 8;
    float m1 = ml1[(size_t)p * 128 + row * 2], l1 = ml1[(size_t)p * 128 + row * 2 + 1];
    float m2 = ml2[(size_t)p * 128 + row * 2], l2 = ml2[(size_t)p * 128 + row * 2 + 1];
    float M = fmaxf(m1, m2);
    float w1 = __expf(m1 - M), w2 = __expf(m2 - M);
    float inv = 1.0f / (l1 * w1 + l2 * w2);
    const unsigned short* o1 = P1 + ((size_t)p * 64 + row) * 512 + c8;
    unsigned short* ap = attn + ((size_t)(b * 2048 + qi * 64 + row)) * 4096 + head * 512 + c8;
    unsigned short res[8];
#pragma unroll
    for (int j = 0; j < 8; ++j)
      res[j] = f2bf((bf2f(o1[j]) * w1 + bf2f(ap[j]) * w2) * inv);
    *(bf16x8*)ap = *(bf16x8*)res;
  }
}

// ---------------- output projection: out += attn @ Wo^T (split-K, fp32 atomics) ----------------
__global__ __launch_bounds__(256) void out_gemm(
    const unsigned short* __restrict__ A, const unsigned short* __restrict__ W,
    float* __restrict__ C) {
  __shared__ __align__(16) unsigned short As[128 * 32];
  __shared__ __align__(16) unsigned short Bs[128 * 32];
  const int tid = threadIdx.x;
  const int wave = tid >> 6, lane = tid & 63, quad = lane >> 4, l16 = lane & 15;
  const int m0 = blockIdx.x * 128, n0 = blockIdx.y * 128;
  const int kb = blockIdx.z * 1024;
  const int wm = (wave >> 1) * 64, wn = (wave & 1) * 64;
  floatx4 acc[4][4];
#pragma unroll
  for (int i = 0; i < 4; ++i)
#pragma unroll
    for (int j = 0; j < 4; ++j) acc[i][j] = (floatx4){0.f, 0.f, 0.f, 0.f};
  const int r0 = wave * 32;
  const int lrow = lane >> 2, lchunk = (lane & 3) * 8;
  for (int k0 = kb; k0 < kb + 1024; k0 += 32) {
    const unsigned short* ga = A + (size_t)(m0 + r0 + lrow) * 4096 + k0 + lchunk;
    const unsigned short* gb = W + (size_t)(n0 + r0 + lrow) * 4096 + k0 + lchunk;
    ldsld16(ga, As + r0 * 32);
    ldsld16(ga + (size_t)16 * 4096, As + r0 * 32 + 512);
    ldsld16(gb, Bs + r0 * 32);
    ldsld16(gb + (size_t)16 * 4096, Bs + r0 * 32 + 512);
    __syncthreads();
    bf16x8 af[4], bw[4];
#pragma unroll
    for (int i = 0; i < 4; ++i) af[i] = *(const bf16x8*)(As + (wm + i * 16 + l16) * 32 + quad * 8);
#pragma unroll
    for (int j = 0; j < 4; ++j) bw[j] = *(const bf16x8*)(Bs + (wn + j * 16 + l16) * 32 + quad * 8);
#pragma unroll
    for (int i = 0; i < 4; ++i)
#pragma unroll
      for (int j = 0; j < 4; ++j) acc[i][j] = MFMA16(af[i], bw[j], acc[i][j]);
    __syncthreads();
  }
#pragma unroll
  for (int i = 0; i < 4; ++i)
#pragma unroll
    for (int j = 0; j < 4; ++j) {
      int gn = n0 + wn + j * 16 + l16;
#pragma unroll
      for (int r = 0; r < 4; ++r) {
        int gm = m0 + wm + i * 16 + quad * 4 + r;
        unsafeAtomicAdd(&C[(size_t)gm * 1024 + gn], acc[i][j][r]);
      }
    }
}

extern "C" void kernel_launch(void* const* d_in, const int* in_sizes, int n_in,
                              void* d_out, int out_size, void* d_ws, size_t ws_size,
                              hipStream_t stream) {
  const float* x  = (const float*)d_in[0];
  const float* Wq = (const float*)d_in[1];
  const float* Wk = (const float*)d_in[2];
  const float* Wv = (const float*)d_in[3];
  const float* Wo = (const float*)d_in[4];
  float* out = (float*)d_out;
  char* ws = (char*)d_ws;
  const size_t MB = 1048576;
  // Layout (peak 154.25 MB split / 138 MB non-split):
  // @0:   xb(pre-qkv) / attnb(post-flash)            32 MB
  // @8/16/24: wqb/wkb/wvb (pre-qkv, inside attn region)
  // @32:  Qb (live qkv..flash) / wob overlay (post-flash) 32 MB
  // @64:  Ktile [16][64][32][536]                     33.5 MB
  // @98:  Vslab [16][64][512][40]                     40 MB
  // @138: P1 16 MB; @154: ml1/ml2 256 KB
  unsigned short* xb    = (unsigned short*)(ws + 0 * MB);
  unsigned short* wqb   = (unsigned short*)(ws + 8 * MB);
  unsigned short* wkb   = (unsigned short*)(ws + 16 * MB);
  unsigned short* wvb   = (unsigned short*)(ws + 24 * MB);
  unsigned short* attnb = (unsigned short*)(ws + 0 * MB);
  unsigned short* Qb    = (unsigned short*)(ws + 32 * MB);
  unsigned short* wob   = (unsigned short*)(ws + 32 * MB);   // cast AFTER flash
  unsigned short* Ktb   = (unsigned short*)(ws + 64 * MB);
  unsigned short* Vtb   = (unsigned short*)(ws + 98 * MB);
  unsigned short* P1    = (unsigned short*)(ws + 138 * MB);
  float* ml1            = (float*)(ws + 154 * MB);
  float* ml2            = (float*)(ws + 154 * MB + 131072);
  const int split = (ws_size >= (size_t)160 * MB) ? 1 : 0;

  hipMemsetAsync(d_out, 0, (size_t)4096 * 1024 * 4, stream);  // out_gemm accumulates

  cast4_k<<<dim3(4096, 4), 256, 0, stream>>>(x, Wq, Wk, Wv, xb, wqb, wkb, wvb);
  qkv_gemm<<<dim3(32, 32, 3), 256, 0, stream>>>(xb, wqb, wkb, wvb, Qb, Ktb, Vtb);
  rope_k<<<65536, 256, 0, stream>>>(Qb, Ktb);
  flash_attn<<<dim3(16, split ? 48 : 32), 256, 0, stream>>>(Qb, Ktb, Vtb, attnb, P1, ml1, ml2, split);
  if (split) combine_k<<<256, 256, 0, stream>>>(P1, ml1, ml2, attnb);
  cast1_k<<<4096, 256, 0, stream>>>(Wo, wob);
  out_gemm<<<dim3(32, 8, 4), 256, 0, stream>>>(attnb, wob, out);
}

// Round 7
// 613.202 us; speedup vs baseline: 3.0625x; 1.1452x over previous
//
#include <hip/hip_runtime.h>

// B=2, T=2048, E=1024, H=8, D=512, HD=4096. bf16 MFMA internally.
// Lessons: (R4) register-array loops must be FULLY unrolled or spill;
// (R5) no cross-wave K/V reuse => latency death; (R6) 2-barrier staging
// serializes DMA (issued after compute, drained with no overlap).
// v7: one WG of 8 waves per CU, q-tile 128, K+V DOUBLE-buffered in LDS
// (160,768 B), ONE barrier per step: bar -> issue DMA(st+1) -> compute(st).
// The vmcnt(0) drain at the barrier then overlaps the whole compute phase.

#define DEV __device__ __forceinline__

using bf16x8  = __attribute__((ext_vector_type(8))) short;
using floatx4 = __attribute__((ext_vector_type(4))) float;

#define MFMA16(a, b, c) __builtin_amdgcn_mfma_f32_16x16x32_bf16((a), (b), (c), 0, 0, 0)

// K padded tiles: [bh][64][32][536] shorts (536 sh = 268 dw = 12 mod 32 -> 2-way, free)
#define KT_BH 1097728
#define KT_TILE 17152
#define KT_ROW 536
// V padded slab: [bh][64][512][40] shorts (40 sh = 20 dw -> 2-way, free)
#define VT_BH 1310720
#define VT_TILE 20480

DEV unsigned short f2bf(float f) {
  union { float f; unsigned int u; } c; c.f = f;
  unsigned int u = c.u + 0x7FFFu + ((c.u >> 16) & 1u);
  return (unsigned short)(u >> 16);
}
DEV float bf2f(unsigned short h) {
  union { unsigned int u; float f; } c; c.u = ((unsigned int)h) << 16;
  return c.f;
}

// async global->LDS, 16B/lane. g is per-lane address; l is wave-uniform base.
DEV void ldsld16(const unsigned short* g, unsigned short* l) {
  __builtin_amdgcn_global_load_lds(
      (__attribute__((address_space(1))) void*)(g),
      (__attribute__((address_space(3))) void*)(l), 16, 0, 0);
}

// ---------------- cast fp32 -> bf16 (x, Wq, Wk, Wv) ----------------
__global__ void cast4_k(const float* __restrict__ x,  const float* __restrict__ wq,
                        const float* __restrict__ wk, const float* __restrict__ wv,
                        unsigned short* __restrict__ xb,  unsigned short* __restrict__ wqb,
                        unsigned short* __restrict__ wkb, unsigned short* __restrict__ wvb) {
  const float* s; unsigned short* d;
  switch (blockIdx.y) {
    case 0: s = x;  d = xb;  break;
    case 1: s = wq; d = wqb; break;
    case 2: s = wk; d = wkb; break;
    default: s = wv; d = wvb; break;
  }
  int i = blockIdx.x * 256 + threadIdx.x;
  float4 v = ((const float4*)s)[i];
  uint2 o;
  o.x = (unsigned int)f2bf(v.x) | ((unsigned int)f2bf(v.y) << 16);
  o.y = (unsigned int)f2bf(v.z) | ((unsigned int)f2bf(v.w) << 16);
  ((uint2*)d)[i] = o;
}

__global__ void cast1_k(const float* __restrict__ s, unsigned short* __restrict__ d) {
  int i = blockIdx.x * 256 + threadIdx.x;
  float4 v = ((const float4*)s)[i];
  uint2 o;
  o.x = (unsigned int)f2bf(v.x) | ((unsigned int)f2bf(v.y) << 16);
  o.y = (unsigned int)f2bf(v.z) | ((unsigned int)f2bf(v.w) << 16);
  ((uint2*)d)[i] = o;
}

// ---------------- QKV projection GEMM ----------------
// Q -> [B,H,T,D]; K -> padded tiles [bh][t/32][32][536]; V -> padded slab
// [bh][t/32][512][40]  (both DMA-ready for flash).
__global__ __launch_bounds__(256) void qkv_gemm(
    const unsigned short* __restrict__ X,
    const unsigned short* __restrict__ Wq, const unsigned short* __restrict__ Wk,
    const unsigned short* __restrict__ Wv,
    unsigned short* __restrict__ Qo, unsigned short* __restrict__ Ko, unsigned short* __restrict__ Vo) {
  __shared__ __align__(16) unsigned short As[128 * 32];
  __shared__ __align__(16) unsigned short Bs[128 * 32];
  const int tid = threadIdx.x;
  const int wave = tid >> 6, lane = tid & 63, quad = lane >> 4, l16 = lane & 15;
  const int m0 = blockIdx.x * 128, n0 = blockIdx.y * 128;
  const int z = blockIdx.z;
  const unsigned short* W = (z == 0) ? Wq : (z == 1) ? Wk : Wv;
  const int wm = (wave >> 1) * 64, wn = (wave & 1) * 64;
  floatx4 acc[4][4];
#pragma unroll
  for (int i = 0; i < 4; ++i)
#pragma unroll
    for (int j = 0; j < 4; ++j) acc[i][j] = (floatx4){0.f, 0.f, 0.f, 0.f};

  const int r0 = wave * 32;
  const int lrow = lane >> 2, lchunk = (lane & 3) * 8;
  for (int k0 = 0; k0 < 1024; k0 += 32) {
    const unsigned short* ga = X + (size_t)(m0 + r0 + lrow) * 1024 + k0 + lchunk;
    const unsigned short* gb = W + (size_t)(n0 + r0 + lrow) * 1024 + k0 + lchunk;
    ldsld16(ga, As + r0 * 32);
    ldsld16(ga + (size_t)16 * 1024, As + r0 * 32 + 512);
    ldsld16(gb, Bs + r0 * 32);
    ldsld16(gb + (size_t)16 * 1024, Bs + r0 * 32 + 512);
    __syncthreads();
    bf16x8 af[4], bw[4];
#pragma unroll
    for (int i = 0; i < 4; ++i) af[i] = *(const bf16x8*)(As + (wm + i * 16 + l16) * 32 + quad * 8);
#pragma unroll
    for (int j = 0; j < 4; ++j) bw[j] = *(const bf16x8*)(Bs + (wn + j * 16 + l16) * 32 + quad * 8);
#pragma unroll
    for (int i = 0; i < 4; ++i)
#pragma unroll
      for (int j = 0; j < 4; ++j) acc[i][j] = MFMA16(af[i], bw[j], acc[i][j]);
    __syncthreads();
  }
#pragma unroll
  for (int i = 0; i < 4; ++i)
#pragma unroll
    for (int j = 0; j < 4; ++j) {
      int gn = n0 + wn + j * 16 + l16;
      int h = gn >> 9, d = gn & 511;
      int gm0 = m0 + wm + i * 16 + quad * 4;
      int b = gm0 >> 11, t0 = gm0 & 2047;   // t0&31 in {0,4,...,28}
      int bh = b * 8 + h;
      if (z == 2) {
        unsigned short pk[4];
#pragma unroll
        for (int r = 0; r < 4; ++r) pk[r] = f2bf(acc[i][j][r]);
        size_t off = (size_t)bh * VT_BH + (t0 >> 5) * VT_TILE + (size_t)d * 40 + (t0 & 31);
        *(uint2*)(Vo + off) = *(uint2*)pk;   // packed 8B, 8B-aligned
      } else if (z == 1) {
        size_t off = (size_t)bh * KT_BH + (t0 >> 5) * KT_TILE + (size_t)(t0 & 31) * KT_ROW + d;
#pragma unroll
        for (int r = 0; r < 4; ++r) Ko[off + (size_t)r * KT_ROW] = f2bf(acc[i][j][r]);
      } else {
        size_t base = ((size_t)(bh * 2048 + t0)) * 512 + d;
#pragma unroll
        for (int r = 0; r < 4; ++r) Qo[base + (size_t)r * 512] = f2bf(acc[i][j][r]);
      }
    }
}

// ---------------- RoPE (Q in place; K in padded tile layout) ----------------
__global__ void rope_k(unsigned short* __restrict__ Q, unsigned short* __restrict__ Kt) {
  int idx = blockIdx.x * 256 + threadIdx.x;
  int r = idx & 8388607;
  int row = r >> 8;                       // bh*2048 + t
  int i = r & 255;
  int t = row & 2047;
  unsigned short* P;
  size_t base;
  if (idx & 8388608) {
    int bh = row >> 11;
    base = (size_t)bh * KT_BH + (t >> 5) * KT_TILE + (size_t)(t & 31) * KT_ROW;
    P = Kt;
  } else {
    base = (size_t)row * 512;
    P = Q;
  }
  float x1 = bf2f(P[base + i]);
  float x2 = bf2f(P[base + i + 256]);
  float freq = expf(-(float)i * 0.03597789207803197f);  // ln(10000)/256
  float ang = (float)t * freq;
  float sv, cv;
  sincosf(ang, &sv, &cv);
  P[base + i]       = f2bf(x1 * cv - x2 * sv);
  P[base + i + 256] = f2bf(x1 * sv + x2 * cv);
}

// ---------------- flash attention v7: 8 waves, double-buffered, 1 barrier/step ----
// WG = 512 threads = 8 waves; q-tile 128 (wave owns 16 q x 512 d); s-tile 32.
// K+V ping-pong buffers; DMA(st+1) issued right after the barrier, overlapping
// the whole compute of step st. grid (16 bh, jobs heavy-first).
__global__ __launch_bounds__(512, 2) void flash_attn(
    const unsigned short* __restrict__ Q, const unsigned short* __restrict__ Kt,
    const unsigned short* __restrict__ Vt, unsigned short* __restrict__ attn,
    unsigned short* __restrict__ P1, float* __restrict__ ml1, float* __restrict__ ml2,
    int split) {
  __shared__ __align__(16) unsigned short Ks[2 * 32 * 536];   // 68608 B
  __shared__ __align__(16) unsigned short Vs[2 * 512 * 40];   // 81920 B
  __shared__ __align__(16) unsigned short Ps[8 * 16 * 40];    // 10240 B (per-wave)
  const int tid = threadIdx.x;
  const int wave = tid >> 6, lane = tid & 63, quad = lane >> 4, l16 = lane & 15;
  const int bh = blockIdx.x, b = bh >> 3, head = bh & 7;
  const int y = blockIdx.y;
  int qi, st0 = 0, stN, om = 0;  // om: 0 direct, 1 chunk0->P1, 2 chunk1->attn unnorm
  if (split) {
    if (y == 0)      { qi = 9; stN = 4 * qi + 4; }
    else if (y == 1) { qi = 8; stN = 4 * qi + 4; }
    else if (y < 14) {
      qi = 15 - ((y - 2) >> 1);
      int mid = 2 * qi + 2;
      if ((y & 1) == 0) { st0 = 0;   stN = mid;        om = 1; }
      else              { st0 = mid; stN = 4 * qi + 4; om = 2; }
    } else { qi = 7 - (y - 14); stN = 4 * qi + 4; }
  } else { qi = 15 - y; stN = 4 * qi + 4; }

  const unsigned short* Qp = Q + ((size_t)bh << 20);
  const unsigned short* Kp = Kt + (size_t)bh * KT_BH;
  const unsigned short* Vp = Vt + (size_t)bh * VT_BH;
  const int qb = qi * 128;
  const int qw0 = qb + wave * 16;

  // Q fragments (A-frag: m=l16, k=quad*8+j), 16 k-steps over 512 d
  bf16x8 qf[16];
  {
    const unsigned short* qrow = Qp + (size_t)(qw0 + l16) * 512 + quad * 8;
#pragma unroll
    for (int ks = 0; ks < 16; ++ks) qf[ks] = *(const bf16x8*)(qrow + ks * 32);
  }
  floatx4 o[32];
#pragma unroll
  for (int n = 0; n < 32; ++n) o[n] = (floatx4){0.f, 0.f, 0.f, 0.f};
  float m_[4], l_[4];
#pragma unroll
  for (int r = 0; r < 4; ++r) { m_[r] = -3.0e38f; l_[r] = 0.f; }

  unsigned short* psw = Ps + wave * 640;  // [16][40]
  const int kc0 = wave * 268;             // K: 2144 16B-chunks / 8 waves
  const int vc0 = wave * 320;             // V: 2560 16B-chunks / 8 waves

  // prologue: DMA st0 into buffer 0
  {
    const unsigned short* gk = Kp + (size_t)st0 * KT_TILE;
    const unsigned short* gv = Vp + (size_t)st0 * VT_TILE;
#pragma unroll
    for (int j = 0; j < 4; ++j)
      ldsld16(gk + (size_t)(kc0 + j * 64 + lane) * 8, Ks + (kc0 + j * 64) * 8);
    if (lane < 12) ldsld16(gk + (size_t)(kc0 + 256 + lane) * 8, Ks + (kc0 + 256) * 8);
#pragma unroll
    for (int j = 0; j < 5; ++j)
      ldsld16(gv + (size_t)(vc0 + j * 64 + lane) * 8, Vs + (vc0 + j * 64) * 8);
  }

  for (int st = st0; st < stN; ++st) {
    const int cur = (st - st0) & 1;
    __syncthreads();  // drains DMA for buf[cur]; all waves done reading buf[cur^1]
    if (st + 1 < stN) {
      const int nxt = cur ^ 1;
      const unsigned short* gk = Kp + (size_t)(st + 1) * KT_TILE;
      const unsigned short* gv = Vp + (size_t)(st + 1) * VT_TILE;
      unsigned short* kd = Ks + nxt * 17152;
      unsigned short* vd = Vs + nxt * 20480;
#pragma unroll
      for (int j = 0; j < 4; ++j)
        ldsld16(gk + (size_t)(kc0 + j * 64 + lane) * 8, kd + (kc0 + j * 64) * 8);
      if (lane < 12) ldsld16(gk + (size_t)(kc0 + 256 + lane) * 8, kd + (kc0 + 256) * 8);
#pragma unroll
      for (int j = 0; j < 5; ++j)
        ldsld16(gv + (size_t)(vc0 + j * 64 + lane) * 8, vd + (vc0 + j * 64) * 8);
    }
    const unsigned short* ksb = Ks + cur * 17152;
    const unsigned short* vsb = Vs + cur * 20480;
    const int s0 = st * 32;
    // ---- QK: S[16q][32s] over 512 d from shared K tile ----
    floatx4 sc0 = (floatx4){0.f, 0.f, 0.f, 0.f}, sc1 = sc0;
#pragma unroll
    for (int ks = 0; ks < 16; ++ks) {
      bf16x8 k0 = *(const bf16x8*)(ksb + (size_t)l16 * 536 + ks * 32 + quad * 8);
      bf16x8 k1 = *(const bf16x8*)(ksb + (size_t)(16 + l16) * 536 + ks * 32 + quad * 8);
      sc0 = MFMA16(qf[ks], k0, sc0);
      sc1 = MFMA16(qf[ks], k1, sc1);
    }
    // ---- online softmax (rows qw0+quad*4+r; cols s0+l16, s0+16+l16) ----
    const float scale = 0.04419417382415922f;  // 1/sqrt(512)
    const int qrow0 = qw0 + quad * 4;
    float pv0[4], pv1[4], mr[4];
#pragma unroll
    for (int r = 0; r < 4; ++r) {
      float a0 = sc0[r] * scale, a1 = sc1[r] * scale;
      if (s0 + l16 > qrow0 + r) a0 = -3.0e38f;
      if (s0 + 16 + l16 > qrow0 + r) a1 = -3.0e38f;
      pv0[r] = a0; pv1[r] = a1;
      mr[r] = fmaxf(a0, a1);
    }
#pragma unroll
    for (int off = 1; off < 16; off <<= 1)
#pragma unroll
      for (int r = 0; r < 4; ++r) mr[r] = fmaxf(mr[r], __shfl_xor(mr[r], off, 64));
    float alpha[4], rs[4];
#pragma unroll
    for (int r = 0; r < 4; ++r) {
      float mn = fmaxf(m_[r], mr[r]);
      alpha[r] = __expf(m_[r] - mn);
      m_[r] = mn;
      float p0 = __expf(pv0[r] - mn);
      float p1 = __expf(pv1[r] - mn);
      rs[r] = p0 + p1;
      psw[(quad * 4 + r) * 40 + l16] = f2bf(p0);
      psw[(quad * 4 + r) * 40 + 16 + l16] = f2bf(p1);
    }
#pragma unroll
    for (int off = 1; off < 16; off <<= 1)
#pragma unroll
      for (int r = 0; r < 4; ++r) rs[r] += __shfl_xor(rs[r], off, 64);
#pragma unroll
    for (int r = 0; r < 4; ++r) l_[r] = l_[r] * alpha[r] + rs[r];
    if (__any(alpha[0] + alpha[1] + alpha[2] + alpha[3] < 4.0f)) {
#pragma unroll
      for (int n = 0; n < 32; ++n)
#pragma unroll
        for (int r = 0; r < 4; ++r) o[n][r] *= alpha[r];
    }
    // ---- PV: O[16][512] += P[16][32] * V[32][512] from shared V tile ----
    bf16x8 pf = *(const bf16x8*)(psw + (size_t)l16 * 40 + quad * 8);  // A-frag of P
#pragma unroll
    for (int nt = 0; nt < 32; ++nt) {
      bf16x8 vf = *(const bf16x8*)(vsb + (size_t)(nt * 16 + l16) * 40 + quad * 8);
      o[nt] = MFMA16(pf, vf, o[nt]);
    }
  }
  // ---- outputs ----
  const int rowi = wave * 16 + quad * 4;  // +r, row within 128-row q-tile
  if (om == 0) {
    float inv[4];
#pragma unroll
    for (int r = 0; r < 4; ++r) inv[r] = 1.0f / l_[r];
    unsigned short* arow = attn + ((size_t)(b * 2048 + qb + rowi)) * 4096 + head * 512 + l16;
#pragma unroll
    for (int nt = 0; nt < 32; ++nt)
#pragma unroll
      for (int r = 0; r < 4; ++r)
        arow[(size_t)r * 4096 + nt * 16] = f2bf(o[nt][r] * inv[r]);
  } else {
    const int p = bh * 6 + (qi - 10);
    float* ml = (om == 1) ? ml1 : ml2;
    if (l16 == 0) {
#pragma unroll
      for (int r = 0; r < 4; ++r) {
        ml[(size_t)p * 256 + (rowi + r) * 2]     = m_[r];
        ml[(size_t)p * 256 + (rowi + r) * 2 + 1] = l_[r];
      }
    }
    if (om == 1) {
      unsigned short* prow = P1 + ((size_t)p * 128 + rowi) * 512 + l16;
#pragma unroll
      for (int nt = 0; nt < 32; ++nt)
#pragma unroll
        for (int r = 0; r < 4; ++r)
          prow[(size_t)r * 512 + nt * 16] = f2bf(o[nt][r]);   // unnormalized
    } else {
      unsigned short* arow = attn + ((size_t)(b * 2048 + qb + rowi)) * 4096 + head * 512 + l16;
#pragma unroll
      for (int nt = 0; nt < 32; ++nt)
#pragma unroll
        for (int r = 0; r < 4; ++r)
          arow[(size_t)r * 4096 + nt * 16] = f2bf(o[nt][r]);  // unnormalized
    }
  }
}

// ---------------- combine split partials (qi in 10..15) ----------------
__global__ void combine_k(const unsigned short* __restrict__ P1,
                          const float* __restrict__ ml1, const float* __restrict__ ml2,
                          unsigned short* __restrict__ attn) {
  const int p = blockIdx.x;  // [0,96)
  const int bh = p / 6, qi = 10 + (p - bh * 6);
  const int b = bh >> 3, head = bh & 7;
  const int tid = threadIdx.x;
#pragma unroll
  for (int it = 0; it < 32; ++it) {
    int idx = it * 256 + tid;        // 128 rows * 64 chunks
    int row = idx >> 6, c8 = (idx & 63) * 8;
    float m1 = ml1[(size_t)p * 256 + row * 2], l1 = ml1[(size_t)p * 256 + row * 2 + 1];
    float m2 = ml2[(size_t)p * 256 + row * 2], l2 = ml2[(size_t)p * 256 + row * 2 + 1];
    float M = fmaxf(m1, m2);
    float w1 = __expf(m1 - M), w2 = __expf(m2 - M);
    float inv = 1.0f / (l1 * w1 + l2 * w2);
    const unsigned short* o1 = P1 + ((size_t)p * 128 + row) * 512 + c8;
    unsigned short* ap = attn + ((size_t)(b * 2048 + qi * 128 + row)) * 4096 + head * 512 + c8;
    unsigned short res[8];
#pragma unroll
    for (int j = 0; j < 8; ++j)
      res[j] = f2bf((bf2f(o1[j]) * w1 + bf2f(ap[j]) * w2) * inv);
    *(bf16x8*)ap = *(bf16x8*)res;
  }
}

// ---------------- output projection: out += attn @ Wo^T (split-K, fp32 atomics) ----------------
__global__ __launch_bounds__(256) void out_gemm(
    const unsigned short* __restrict__ A, const unsigned short* __restrict__ W,
    float* __restrict__ C) {
  __shared__ __align__(16) unsigned short As[128 * 32];
  __shared__ __align__(16) unsigned short Bs[128 * 32];
  const int tid = threadIdx.x;
  const int wave = tid >> 6, lane = tid & 63, quad = lane >> 4, l16 = lane & 15;
  const int m0 = blockIdx.x * 128, n0 = blockIdx.y * 128;
  const int kb = blockIdx.z * 1024;
  const int wm = (wave >> 1) * 64, wn = (wave & 1) * 64;
  floatx4 acc[4][4];
#pragma unroll
  for (int i = 0; i < 4; ++i)
#pragma unroll
    for (int j = 0; j < 4; ++j) acc[i][j] = (floatx4){0.f, 0.f, 0.f, 0.f};
  const int r0 = wave * 32;
  const int lrow = lane >> 2, lchunk = (lane & 3) * 8;
  for (int k0 = kb; k0 < kb + 1024; k0 += 32) {
    const unsigned short* ga = A + (size_t)(m0 + r0 + lrow) * 4096 + k0 + lchunk;
    const unsigned short* gb = W + (size_t)(n0 + r0 + lrow) * 4096 + k0 + lchunk;
    ldsld16(ga, As + r0 * 32);
    ldsld16(ga + (size_t)16 * 4096, As + r0 * 32 + 512);
    ldsld16(gb, Bs + r0 * 32);
    ldsld16(gb + (size_t)16 * 4096, Bs + r0 * 32 + 512);
    __syncthreads();
    bf16x8 af[4], bw[4];
#pragma unroll
    for (int i = 0; i < 4; ++i) af[i] = *(const bf16x8*)(As + (wm + i * 16 + l16) * 32 + quad * 8);
#pragma unroll
    for (int j = 0; j < 4; ++j) bw[j] = *(const bf16x8*)(Bs + (wn + j * 16 + l16) * 32 + quad * 8);
#pragma unroll
    for (int i = 0; i < 4; ++i)
#pragma unroll
      for (int j = 0; j < 4; ++j) acc[i][j] = MFMA16(af[i], bw[j], acc[i][j]);
    __syncthreads();
  }
#pragma unroll
  for (int i = 0; i < 4; ++i)
#pragma unroll
    for (int j = 0; j < 4; ++j) {
      int gn = n0 + wn + j * 16 + l16;
#pragma unroll
      for (int r = 0; r < 4; ++r) {
        int gm = m0 + wm + i * 16 + quad * 4 + r;
        unsafeAtomicAdd(&C[(size_t)gm * 1024 + gn], acc[i][j][r]);
      }
    }
}

extern "C" void kernel_launch(void* const* d_in, const int* in_sizes, int n_in,
                              void* d_out, int out_size, void* d_ws, size_t ws_size,
                              hipStream_t stream) {
  const float* x  = (const float*)d_in[0];
  const float* Wq = (const float*)d_in[1];
  const float* Wk = (const float*)d_in[2];
  const float* Wv = (const float*)d_in[3];
  const float* Wo = (const float*)d_in[4];
  float* out = (float*)d_out;
  char* ws = (char*)d_ws;
  const size_t MB = 1048576;
  // Layout: @0 xb/attnb 32MB; @8/16/24 wqb/wkb/wvb (pre-qkv); @32 Qb / wob
  // overlay (post-flash); @64 Ktile 33.5MB; @98 Vslab 40MB; @138 P1 12.6MB;
  // @154 ml1/ml2 (96*256 floats each).
  unsigned short* xb    = (unsigned short*)(ws + 0 * MB);
  unsigned short* wqb   = (unsigned short*)(ws + 8 * MB);
  unsigned short* wkb   = (unsigned short*)(ws + 16 * MB);
  unsigned short* wvb   = (unsigned short*)(ws + 24 * MB);
  unsigned short* attnb = (unsigned short*)(ws + 0 * MB);
  unsigned short* Qb    = (unsigned short*)(ws + 32 * MB);
  unsigned short* wob   = (unsigned short*)(ws + 32 * MB);   // cast AFTER flash
  unsigned short* Ktb   = (unsigned short*)(ws + 64 * MB);
  unsigned short* Vtb   = (unsigned short*)(ws + 98 * MB);
  unsigned short* P1    = (unsigned short*)(ws + 138 * MB);
  float* ml1            = (float*)(ws + 154 * MB);
  float* ml2            = (float*)(ws + 154 * MB + 131072);
  const int split = (ws_size >= (size_t)160 * MB) ? 1 : 0;

  hipMemsetAsync(d_out, 0, (size_t)4096 * 1024 * 4, stream);  // out_gemm accumulates

  cast4_k<<<dim3(4096, 4), 256, 0, stream>>>(x, Wq, Wk, Wv, xb, wqb, wkb, wvb);
  qkv_gemm<<<dim3(32, 32, 3), 256, 0, stream>>>(xb, wqb, wkb, wvb, Qb, Ktb, Vtb);
  rope_k<<<65536, 256, 0, stream>>>(Qb, Ktb);
  flash_attn<<<dim3(16, split ? 22 : 16), 512, 0, stream>>>(Qb, Ktb, Vtb, attnb, P1, ml1, ml2, split);
  if (split) combine_k<<<96, 256, 0, stream>>>(P1, ml1, ml2, attnb);
  cast1_k<<<4096, 256, 0, stream>>>(Wo, wob);
  out_gemm<<<dim3(32, 8, 4), 256, 0, stream>>>(attnb, wob, out);
}